// Round 1
// baseline (1645.041 us; speedup 1.0000x reference)
//
#include <hip/hip_runtime.h>
#include <math.h>

// SoftclDiceLoss on (B,C,D,H,W) = (2,1,64,256,256) float32.
// Pipeline:
//   pred = sigmoid(logits)*mask ; tgt = target*mask
//   skel(v): 5x { mp = 7-point-cross min(v); v = relu(v - (max3x3x3(mp) - mp)) }
//   clrecall = (sum(skel(tgt)*pred)+eps)/(sum(skel(tgt))+eps)
//   clacc    = (sum(skel(pred)*tgt)+eps)/(sum(skel(pred))+eps)
//   out = 1 - 2*cr*ca/(cr+ca+eps)

constexpr int B  = 2;
constexpr int D  = 64;
constexpr int H  = 256;
constexpr int W  = 256;
constexpr int HW = H * W;           // 65536
constexpr int NV = B * D * H * W;   // 8388608 == 32768 * 256

__global__ __launch_bounds__(256) void prep_kernel(const float* __restrict__ logits,
                                                   const float* __restrict__ target,
                                                   const float* __restrict__ mask,
                                                   float* __restrict__ pred,
                                                   float* __restrict__ tgt,
                                                   float* __restrict__ x) {
    int i = blockIdx.x * 256 + threadIdx.x;
    float m = mask[i];
    float p = (1.0f / (1.0f + expf(-logits[i]))) * m;
    float t = target[i] * m;
    pred[i] = p;
    tgt[i]  = t;
    x[i]    = t;   // first skeletonization runs on tgt
}

// mp = min over the 7-point cross {center, d±1, h±1, w±1}, OOB excluded.
__global__ __launch_bounds__(256) void minpool_kernel(const float* __restrict__ x,
                                                      float* __restrict__ mp) {
    int i = blockIdx.x * 256 + threadIdx.x;
    int w = i & (W - 1);
    int h = (i >> 8) & (H - 1);
    int d = (i >> 16) & (D - 1);
    float m = x[i];
    if (w > 0)     m = fminf(m, x[i - 1]);
    if (w < W - 1) m = fminf(m, x[i + 1]);
    if (h > 0)     m = fminf(m, x[i - W]);
    if (h < H - 1) m = fminf(m, x[i + W]);
    if (d > 0)     m = fminf(m, x[i - HW]);
    if (d < D - 1) m = fminf(m, x[i + HW]);
    mp[i] = m;
}

// x = relu(x - relu(max3x3x3(mp) - mp)); window always contains center so
// max3x3x3(mp) >= mp and the inner relu is the identity on (mx - c).
__global__ __launch_bounds__(256) void update_kernel(const float* __restrict__ mp,
                                                     float* __restrict__ x) {
    int i = blockIdx.x * 256 + threadIdx.x;
    int w = i & (W - 1);
    int h = (i >> 8) & (H - 1);
    int d = (i >> 16) & (D - 1);
    float c  = mp[i];
    float mx = c;
    int dz0 = (d > 0) ? -1 : 0, dz1 = (d < D - 1) ? 1 : 0;
    int dy0 = (h > 0) ? -1 : 0, dy1 = (h < H - 1) ? 1 : 0;
    int dx0 = (w > 0) ? -1 : 0, dx1 = (w < W - 1) ? 1 : 0;
    for (int dz = dz0; dz <= dz1; ++dz) {
        for (int dy = dy0; dy <= dy1; ++dy) {
            const float* row = mp + i + dz * HW + dy * W;
            for (int dx = dx0; dx <= dx1; ++dx) {
                mx = fmaxf(mx, row[dx]);
            }
        }
    }
    float contour = mx - c;                 // >= 0
    x[i] = fmaxf(x[i] - contour, 0.0f);
}

// acc[0] += sum(x*other), acc[1] += sum(x). If x_set != null, x_set[i] = other[i]
// afterwards (used to reset the working buffer to pred for the second pass).
__global__ __launch_bounds__(256) void reduce_kernel(const float* __restrict__ x,
                                                     const float* __restrict__ other,
                                                     float* __restrict__ x_set,
                                                     double* __restrict__ acc) {
    double s0 = 0.0, s1 = 0.0;
    int stride = gridDim.x * blockDim.x;
    for (int i = blockIdx.x * blockDim.x + threadIdx.x; i < NV; i += stride) {
        float xv = x[i];
        float ov = other[i];
        s0 += (double)(xv * ov);
        s1 += (double)xv;
        if (x_set) x_set[i] = ov;
    }
    for (int off = 32; off > 0; off >>= 1) {
        s0 += __shfl_down(s0, off, 64);
        s1 += __shfl_down(s1, off, 64);
    }
    __shared__ double sm0[4], sm1[4];
    int lane = threadIdx.x & 63;
    int wv   = threadIdx.x >> 6;
    if (lane == 0) { sm0[wv] = s0; sm1[wv] = s1; }
    __syncthreads();
    if (threadIdx.x == 0) {
        atomicAdd(&acc[0], sm0[0] + sm0[1] + sm0[2] + sm0[3]);
        atomicAdd(&acc[1], sm1[0] + sm1[1] + sm1[2] + sm1[3]);
    }
}

__global__ void final_kernel(const double* __restrict__ acc, float* __restrict__ out) {
    double clrecall = (acc[0] + 1e-12) / (acc[1] + 1e-12);
    double clacc    = (acc[2] + 1e-12) / (acc[3] + 1e-12);
    double cldice   = 2.0 * clrecall * clacc / (clrecall + clacc + 1e-12);
    out[0] = (float)(1.0 - cldice);
}

extern "C" void kernel_launch(void* const* d_in, const int* in_sizes, int n_in,
                              void* d_out, int out_size, void* d_ws, size_t ws_size,
                              hipStream_t stream) {
    const float* logits = (const float*)d_in[0];
    const float* target = (const float*)d_in[1];
    const float* mask   = (const float*)d_in[2];
    float* out = (float*)d_out;

    // Workspace layout (floats): pred | tgt | x | mp | acc(4 doubles)
    float* pred = (float*)d_ws;
    float* tgt  = pred + NV;
    float* x    = tgt + NV;
    float* mp   = x + NV;
    double* acc = (double*)(mp + NV);   // offset 128 MiB, 8B-aligned

    hipMemsetAsync(acc, 0, 4 * sizeof(double), stream);

    dim3 blk(256);
    dim3 grd(NV / 256);   // exact: 32768 blocks

    prep_kernel<<<grd, blk, 0, stream>>>(logits, target, mask, pred, tgt, x);

    for (int it = 0; it < 5; ++it) {
        minpool_kernel<<<grd, blk, 0, stream>>>(x, mp);
        update_kernel<<<grd, blk, 0, stream>>>(mp, x);
    }
    // skel(tgt) stats vs pred, then reset x = pred
    reduce_kernel<<<2048, blk, 0, stream>>>(x, pred, x, acc);

    for (int it = 0; it < 5; ++it) {
        minpool_kernel<<<grd, blk, 0, stream>>>(x, mp);
        update_kernel<<<grd, blk, 0, stream>>>(mp, x);
    }
    // skel(pred) stats vs tgt
    reduce_kernel<<<2048, blk, 0, stream>>>(x, tgt, nullptr, acc + 2);

    final_kernel<<<1, 1, 0, stream>>>(acc, out);
}

// Round 2
// 877.917 us; speedup vs baseline: 1.8738x; 1.8738x over previous
//
#include <hip/hip_runtime.h>
#include <math.h>

// SoftclDiceLoss on (B,C,D,H,W) = (2,1,64,256,256) float32.
// Fused per-iteration skeletonize kernel:
//   mp  = 7-point cross min of x            (computed in LDS)
//   mw  = row-max (W) of mp                 (separable 3x3x3 max, stage 1)
//   mhw = col-max (H) of mw                 (stage 2)
//   out = relu(x - (max_q(mhw) - mp))       (stage 3: max over 3 D-planes)
// Block = 32x32 (H,W) tile marching a 16-plane D chunk with rolling LDS rings.

constexpr int B  = 2;
constexpr int D  = 64;
constexpr int H  = 256;
constexpr int W  = 256;
constexpr int HW = H * W;           // 65536
constexpr int NV = B * D * H * W;   // 8388608

constexpr int TH = 32, TW = 32;     // output tile
constexpr int CD = 16;              // D-chunk per block
constexpr int XH = TH + 4, XW = TW + 4;   // 36x36 x-plane (halo 2)
constexpr int MH = TH + 2, MWd = TW + 2;  // 34x34 mp-plane (halo 1)

__global__ __launch_bounds__(256) void prep_kernel(const float* __restrict__ logits,
                                                   const float* __restrict__ target,
                                                   const float* __restrict__ mask,
                                                   float* __restrict__ pred,
                                                   float* __restrict__ tgt) {
    int i = blockIdx.x * 256 + threadIdx.x;
    float m = mask[i];
    float p = (1.0f / (1.0f + expf(-logits[i]))) * m;
    float t = target[i] * m;
    pred[i] = p;
    tgt[i]  = t;
}

__global__ __launch_bounds__(256) void skel_iter_kernel(const float* __restrict__ xin,
                                                        float* __restrict__ xout) {
    __shared__ float sx[4][XH * XW];      // x planes, ring of 4       (20.25 KB)
    __shared__ float smp[3][MH * MWd];    // cross-min planes, ring 3  (13.55 KB)
    __shared__ float smw[3][MH * TW];     // row-max of mp, ring 3     (12.75 KB)
    __shared__ float smh[3][TH * TW];     // col-max of mw, ring 3     (12.00 KB)

    int bx  = blockIdx.x;
    int w0  = (bx & 7) * TW;
    int h0  = ((bx >> 3) & 7) * TH;
    int gd0 = ((bx >> 6) & 3) * CD;
    int b   = bx >> 8;
    int tid = threadIdx.x;

    const float* xb = xin + b * (D * HW);
    float*       ob = xout + b * (D * HW);

    auto load_plane = [&](int p) {
        float* dst = sx[p & 3];
        if (p < 0 || p >= D) {
            for (int i = tid; i < XH * XW; i += 256) dst[i] = INFINITY;
        } else {
            const float* src = xb + p * HW;
            for (int i = tid; i < XH * XW; i += 256) {
                int lh = i / XW, lw = i - lh * XW;
                int gh = h0 - 2 + lh, gw = w0 - 2 + lw;
                float v = INFINITY;
                if (gh >= 0 && gh < H && gw >= 0 && gw < W) v = src[gh * W + gw];
                dst[i] = v;
            }
        }
    };

    load_plane(gd0 - 2);
    load_plane(gd0 - 1);

    for (int q = gd0 - 1; q <= gd0 + CD; ++q) {
        load_plane(q + 1);
        __syncthreads();

        if (q >= 0 && q < D) {
            // mp[q]: 7-point cross min (OOB neighbors excluded via +INF fill;
            // globally-OOB centers set to -INF so the max stages ignore them)
            const float* xm = sx[(q - 1) & 3];
            const float* xc = sx[q & 3];
            const float* xp = sx[(q + 1) & 3];
            float* mp = smp[(q + 3) % 3];
            for (int i = tid; i < MH * MWd; i += 256) {
                int lh = i / MWd, lw = i - lh * MWd;
                int gh = h0 - 1 + lh, gw = w0 - 1 + lw;
                float v;
                if (gh < 0 || gh >= H || gw < 0 || gw >= W) {
                    v = -INFINITY;
                } else {
                    int ci = (lh + 1) * XW + (lw + 1);
                    v = xc[ci];
                    v = fminf(v, xc[ci - 1]);
                    v = fminf(v, xc[ci + 1]);
                    v = fminf(v, xc[ci - XW]);
                    v = fminf(v, xc[ci + XW]);
                    v = fminf(v, xm[ci]);
                    v = fminf(v, xp[ci]);
                }
                mp[i] = v;
            }
            __syncthreads();

            // mw[q]: max over w-1..w+1 of mp (rows keep h-halo)
            float* mw = smw[(q + 3) % 3];
            for (int i = tid; i < MH * TW; i += 256) {
                int lh = i >> 5, lw = i & 31;
                const float* r = mp + lh * MWd + lw;
                mw[i] = fmaxf(fmaxf(r[0], r[1]), r[2]);
            }
            __syncthreads();

            // mh[q]: max over h-1..h+1 of mw
            float* mh = smh[(q + 3) % 3];
            for (int i = tid; i < TH * TW; i += 256) {
                int lh = i >> 5, lw = i & 31;
                const float* c = mw + lh * TW + lw;
                mh[i] = fmaxf(fmaxf(c[0], c[TW]), c[2 * TW]);
            }
        } else {
            // OOB plane: its contribution to the D-direction max is -INF
            float* mh = smh[(q + 3) % 3];
            for (int i = tid; i < TH * TW; i += 256) mh[i] = -INFINITY;
        }
        __syncthreads();

        int d = q - 1;
        if (d >= gd0 && d < gd0 + CD) {
            const float* m0 = smh[(d + 2) % 3];
            const float* m1 = smh[(d + 3) % 3];
            const float* m2 = smh[(d + 4) % 3];
            const float* mpd = smp[(d + 3) % 3];
            const float* xd  = sx[d & 3];
            float* orow = ob + d * HW;
            for (int i = tid; i < TH * TW; i += 256) {
                int lh = i >> 5, lw = i & 31;
                float mx = fmaxf(fmaxf(m0[i], m1[i]), m2[i]);
                float c  = mpd[(lh + 1) * MWd + (lw + 1)];
                float xv = xd[(lh + 2) * XW + (lw + 2)];
                orow[(h0 + lh) * W + (w0 + lw)] = fmaxf(xv - (mx - c), 0.0f);
            }
        }
    }
}

// acc[0] += sum(x*other), acc[1] += sum(x)
__global__ __launch_bounds__(256) void reduce_kernel(const float* __restrict__ x,
                                                     const float* __restrict__ other,
                                                     double* __restrict__ acc) {
    double s0 = 0.0, s1 = 0.0;
    int stride = gridDim.x * blockDim.x;
    for (int i = blockIdx.x * blockDim.x + threadIdx.x; i < NV; i += stride) {
        float xv = x[i];
        float ov = other[i];
        s0 += (double)(xv * ov);
        s1 += (double)xv;
    }
    for (int off = 32; off > 0; off >>= 1) {
        s0 += __shfl_down(s0, off, 64);
        s1 += __shfl_down(s1, off, 64);
    }
    __shared__ double sm0[4], sm1[4];
    int lane = threadIdx.x & 63;
    int wv   = threadIdx.x >> 6;
    if (lane == 0) { sm0[wv] = s0; sm1[wv] = s1; }
    __syncthreads();
    if (threadIdx.x == 0) {
        atomicAdd(&acc[0], sm0[0] + sm0[1] + sm0[2] + sm0[3]);
        atomicAdd(&acc[1], sm1[0] + sm1[1] + sm1[2] + sm1[3]);
    }
}

__global__ void final_kernel(const double* __restrict__ acc, float* __restrict__ out) {
    double clrecall = (acc[0] + 1e-12) / (acc[1] + 1e-12);
    double clacc    = (acc[2] + 1e-12) / (acc[3] + 1e-12);
    double cldice   = 2.0 * clrecall * clacc / (clrecall + clacc + 1e-12);
    out[0] = (float)(1.0 - cldice);
}

extern "C" void kernel_launch(void* const* d_in, const int* in_sizes, int n_in,
                              void* d_out, int out_size, void* d_ws, size_t ws_size,
                              hipStream_t stream) {
    const float* logits = (const float*)d_in[0];
    const float* target = (const float*)d_in[1];
    const float* mask   = (const float*)d_in[2];
    float* out = (float*)d_out;

    // Workspace layout (floats): pred | tgt | xA | xB | acc(4 doubles)
    float* pred = (float*)d_ws;
    float* tgt  = pred + NV;
    float* xA   = tgt + NV;
    float* xB   = xA + NV;
    double* acc = (double*)(xB + NV);

    hipMemsetAsync(acc, 0, 4 * sizeof(double), stream);

    dim3 blk(256);
    prep_kernel<<<dim3(NV / 256), blk, 0, stream>>>(logits, target, mask, pred, tgt);

    dim3 sgrd(512);  // 2 batches x 4 D-chunks x 8x8 tiles

    // skeletonize(tgt): tgt -> A -> B -> A -> B -> A
    for (int it = 0; it < 5; ++it) {
        const float* in = (it == 0) ? tgt : ((it & 1) ? xA : xB);
        float* outb = (it & 1) ? xB : xA;
        skel_iter_kernel<<<sgrd, blk, 0, stream>>>(in, outb);
    }
    reduce_kernel<<<2048, blk, 0, stream>>>(xA, pred, acc);

    // skeletonize(pred): pred -> A -> B -> A -> B -> A
    for (int it = 0; it < 5; ++it) {
        const float* in = (it == 0) ? pred : ((it & 1) ? xA : xB);
        float* outb = (it & 1) ? xB : xA;
        skel_iter_kernel<<<sgrd, blk, 0, stream>>>(in, outb);
    }
    reduce_kernel<<<2048, blk, 0, stream>>>(xA, tgt, acc + 2);

    final_kernel<<<1, 1, 0, stream>>>(acc, out);
}

// Round 3
// 866.115 us; speedup vs baseline: 1.8993x; 1.0136x over previous
//
#include <hip/hip_runtime.h>
#include <math.h>

// SoftclDiceLoss on (B,C,D,H,W) = (2,1,64,256,256) float32.
// Fused per-iteration skeletonize kernel, latency-optimized:
//   mp  = 7-point cross min of x   (LDS, ring of 3)
//   out = relu(x - (max27(mp) - mp))  (27-point max read directly from mp rings)
// Block = 32x32 (H,W) tile marching an 8-plane D chunk. 2 barriers per plane.
// LDS ~34.6 KB -> 4 blocks/CU, grid 1024 = exactly 4/CU.

constexpr int B  = 2;
constexpr int D  = 64;
constexpr int H  = 256;
constexpr int W  = 256;
constexpr int HW = H * W;           // 65536
constexpr int NV = B * D * H * W;   // 8388608

constexpr int TH = 32, TW = 32;     // output tile
constexpr int CD = 8;               // D-chunk per block
constexpr int XH = TH + 4, XW = TW + 4;   // 36x36 x-plane (halo 2)
constexpr int MH = TH + 2, MWd = TW + 2;  // 34x34 mp-plane (halo 1)

__global__ __launch_bounds__(256) void prep_kernel(const float* __restrict__ logits,
                                                   const float* __restrict__ target,
                                                   const float* __restrict__ mask,
                                                   float* __restrict__ pred,
                                                   float* __restrict__ tgt) {
    int i = blockIdx.x * 256 + threadIdx.x;
    float m = mask[i];
    float p = (1.0f / (1.0f + expf(-logits[i]))) * m;
    float t = target[i] * m;
    pred[i] = p;
    tgt[i]  = t;
}

__global__ __launch_bounds__(256) void skel_iter_kernel(const float* __restrict__ xin,
                                                        float* __restrict__ xout) {
    __shared__ float sx[4][XH * XW];    // x planes, ring of 4   (20.25 KB)
    __shared__ float smp[3][MH * MWd];  // cross-min planes, ring of 3 (13.55 KB)

    int bx  = blockIdx.x;
    int w0  = (bx & 7) * TW;
    int h0  = ((bx >> 3) & 7) * TH;
    int gd0 = ((bx >> 6) & 7) * CD;
    int b   = bx >> 9;
    int tid = threadIdx.x;
    int lw  = tid & 31;   // lane col
    int lr  = tid >> 5;   // thread row group (0..7)

    const float* xb = xin + b * (D * HW);
    float*       ob = xout + b * (D * HW);

    auto load_plane = [&](int p) {
        float* dst = sx[p & 3];
        if (p < 0 || p >= D) {
            for (int r = lr; r < XH; r += 8)
                for (int c = lw; c < XW; c += 32)
                    dst[r * XW + c] = INFINITY;
        } else {
            const float* src = xb + p * HW;
            for (int r = lr; r < XH; r += 8) {
                int gh = h0 - 2 + r;
                for (int c = lw; c < XW; c += 32) {
                    int gw = w0 - 2 + c;
                    float v = INFINITY;
                    if (gh >= 0 && gh < H && gw >= 0 && gw < W) v = src[gh * W + gw];
                    dst[r * XW + c] = v;
                }
            }
        }
    };

    load_plane(gd0 - 2);
    load_plane(gd0 - 1);

    for (int q = gd0 - 1; q <= gd0 + CD; ++q) {
        load_plane(q + 1);
        __syncthreads();   // x[q+1] ready; prior out-stage reads of x/mp done

        // mp[q]: 7-point cross min (OOB x-neighbors excluded via +INF fill;
        // globally-OOB centers / planes set to -INF so the max stage ignores them)
        float* mp = smp[(q + 3) % 3];
        if (q >= 0 && q < D) {
            const float* xm = sx[(q - 1) & 3];
            const float* xc = sx[q & 3];
            const float* xp = sx[(q + 1) & 3];
            for (int r = lr; r < MH; r += 8) {
                int gh = h0 - 1 + r;
                for (int c = lw; c < MWd; c += 32) {
                    int gw = w0 - 1 + c;
                    float v;
                    if (gh < 0 || gh >= H || gw < 0 || gw >= W) {
                        v = -INFINITY;
                    } else {
                        int ci = (r + 1) * XW + (c + 1);
                        v = xc[ci];
                        v = fminf(v, xc[ci - 1]);
                        v = fminf(v, xc[ci + 1]);
                        v = fminf(v, xc[ci - XW]);
                        v = fminf(v, xc[ci + XW]);
                        v = fminf(v, xm[ci]);
                        v = fminf(v, xp[ci]);
                    }
                    mp[r * MWd + c] = v;
                }
            }
        } else {
            for (int r = lr; r < MH; r += 8)
                for (int c = lw; c < MWd; c += 32)
                    mp[r * MWd + c] = -INFINITY;
        }
        __syncthreads();   // mp[q] ready

        int d = q - 1;
        if (d >= gd0 && d < gd0 + CD) {
            const float* m0 = smp[(q + 1) % 3];   // mp[d-1]
            const float* m1 = smp[(q + 2) % 3];   // mp[d]
            const float* m2 = smp[(q + 3) % 3];   // mp[d+1]
            const float* xd = sx[d & 3];
            float* orow = ob + d * HW;
            for (int r = lr; r < TH; r += 8) {
                int ci = (r + 1) * MWd + (lw + 1);
                float cv = m1[ci];
                float mx = cv;
                #pragma unroll
                for (int dy = -1; dy <= 1; ++dy) {
                    int o = ci + dy * MWd;
                    mx = fmaxf(mx, fmaxf(fmaxf(m0[o - 1], m0[o]), m0[o + 1]));
                    mx = fmaxf(mx, fmaxf(m1[o - 1], m1[o + 1]));
                    if (dy != 0) mx = fmaxf(mx, m1[o]);
                    mx = fmaxf(mx, fmaxf(fmaxf(m2[o - 1], m2[o]), m2[o + 1]));
                }
                float xv = xd[(r + 2) * XW + (lw + 2)];
                orow[(h0 + r) * W + (w0 + lw)] = fmaxf(xv - (mx - cv), 0.0f);
            }
        }
        // next iteration's load is preceded by sync A, protecting x/mp reads
    }
}

// acc[0] += sum(x*other), acc[1] += sum(x)
__global__ __launch_bounds__(256) void reduce_kernel(const float* __restrict__ x,
                                                     const float* __restrict__ other,
                                                     double* __restrict__ acc) {
    double s0 = 0.0, s1 = 0.0;
    int stride = gridDim.x * blockDim.x;
    for (int i = blockIdx.x * blockDim.x + threadIdx.x; i < NV; i += stride) {
        float xv = x[i];
        float ov = other[i];
        s0 += (double)(xv * ov);
        s1 += (double)xv;
    }
    for (int off = 32; off > 0; off >>= 1) {
        s0 += __shfl_down(s0, off, 64);
        s1 += __shfl_down(s1, off, 64);
    }
    __shared__ double sm0[4], sm1[4];
    int lane = threadIdx.x & 63;
    int wv   = threadIdx.x >> 6;
    if (lane == 0) { sm0[wv] = s0; sm1[wv] = s1; }
    __syncthreads();
    if (threadIdx.x == 0) {
        atomicAdd(&acc[0], sm0[0] + sm0[1] + sm0[2] + sm0[3]);
        atomicAdd(&acc[1], sm1[0] + sm1[1] + sm1[2] + sm1[3]);
    }
}

__global__ void final_kernel(const double* __restrict__ acc, float* __restrict__ out) {
    double clrecall = (acc[0] + 1e-12) / (acc[1] + 1e-12);
    double clacc    = (acc[2] + 1e-12) / (acc[3] + 1e-12);
    double cldice   = 2.0 * clrecall * clacc / (clrecall + clacc + 1e-12);
    out[0] = (float)(1.0 - cldice);
}

extern "C" void kernel_launch(void* const* d_in, const int* in_sizes, int n_in,
                              void* d_out, int out_size, void* d_ws, size_t ws_size,
                              hipStream_t stream) {
    const float* logits = (const float*)d_in[0];
    const float* target = (const float*)d_in[1];
    const float* mask   = (const float*)d_in[2];
    float* out = (float*)d_out;

    // Workspace layout (floats): pred | tgt | xA | xB | acc(4 doubles)
    float* pred = (float*)d_ws;
    float* tgt  = pred + NV;
    float* xA   = tgt + NV;
    float* xB   = xA + NV;
    double* acc = (double*)(xB + NV);

    hipMemsetAsync(acc, 0, 4 * sizeof(double), stream);

    dim3 blk(256);
    prep_kernel<<<dim3(NV / 256), blk, 0, stream>>>(logits, target, mask, pred, tgt);

    dim3 sgrd(1024);  // 2 batches x 8 D-chunks x 8x8 tiles = 4 blocks/CU

    // skeletonize(tgt): tgt -> A -> B -> A -> B -> A
    for (int it = 0; it < 5; ++it) {
        const float* in = (it == 0) ? tgt : ((it & 1) ? xA : xB);
        float* outb = (it & 1) ? xB : xA;
        skel_iter_kernel<<<sgrd, blk, 0, stream>>>(in, outb);
    }
    reduce_kernel<<<2048, blk, 0, stream>>>(xA, pred, acc);

    // skeletonize(pred): pred -> A -> B -> A -> B -> A
    for (int it = 0; it < 5; ++it) {
        const float* in = (it == 0) ? pred : ((it & 1) ? xA : xB);
        float* outb = (it & 1) ? xB : xA;
        skel_iter_kernel<<<sgrd, blk, 0, stream>>>(in, outb);
    }
    reduce_kernel<<<2048, blk, 0, stream>>>(xA, tgt, acc + 2);

    final_kernel<<<1, 1, 0, stream>>>(acc, out);
}

// Round 4
// 581.113 us; speedup vs baseline: 2.8308x; 1.4904x over previous
//
#include <hip/hip_runtime.h>
#include <math.h>

// SoftclDiceLoss on (B,C,D,H,W) = (2,1,64,256,256) float32.
// Vectorized fused skeletonize iteration:
//   mp[q]  = 7-point cross min of x (LDS, single plane buffer, float4 ops)
//   hw9[q] = 3x3 HW-max of mp[q]   (registers, rotating ring of 3)
//   out[d=q-1] = relu(x - (max(hw9[d-1],hw9[d],hw9[d+1]) - mpc[d]))
// All LDS traffic is ds_read_b128/ds_write_b128; W-neighbors via register
// component shifts. 2 barriers/plane. LDS ~28.4 KB -> 4+ blocks/CU.
// Final iteration of each skeletonization fuses the product/sum reduction.

constexpr int B  = 2;
constexpr int D  = 64;
constexpr int H  = 256;
constexpr int W  = 256;
constexpr int HW = H * W;           // 65536
constexpr int NV = B * D * H * W;   // 8388608

constexpr int TH = 32, TW = 32;     // output tile
constexpr int CD = 8;               // D-chunk per block
constexpr int XS = 40;              // LDS row stride (floats) for x and mp
constexpr int XH = 36;              // x plane rows (halo 2)
// x plane covers global cols w0-4 .. w0+35 (aligned float4 window)
// mp plane rows 0..33 -> global h0-1+r ; mp col c -> global w0-1+c

__device__ __forceinline__ float4 vmin4(float4 a, float4 b) {
    return make_float4(fminf(a.x,b.x), fminf(a.y,b.y), fminf(a.z,b.z), fminf(a.w,b.w));
}
__device__ __forceinline__ float4 vmax4(float4 a, float4 b) {
    return make_float4(fmaxf(a.x,b.x), fmaxf(a.y,b.y), fmaxf(a.z,b.z), fmaxf(a.w,b.w));
}
__device__ __forceinline__ float4 sh1(float4 a, float4 b) { return make_float4(a.y,a.z,a.w,b.x); }
__device__ __forceinline__ float4 sh2(float4 a, float4 b) { return make_float4(a.z,a.w,b.x,b.y); }
__device__ __forceinline__ float4 sh3(float4 a, float4 b) { return make_float4(a.w,b.x,b.y,b.z); }

__global__ __launch_bounds__(256) void prep_kernel(const float* __restrict__ logits,
                                                   const float* __restrict__ target,
                                                   const float* __restrict__ mask,
                                                   float* __restrict__ pred,
                                                   float* __restrict__ tgt) {
    int i = (blockIdx.x * 256 + threadIdx.x) * 4;
    float4 lg = *(const float4*)(logits + i);
    float4 tg = *(const float4*)(target + i);
    float4 mk = *(const float4*)(mask + i);
    float4 p, t;
    p.x = (1.0f/(1.0f+expf(-lg.x)))*mk.x;  t.x = tg.x*mk.x;
    p.y = (1.0f/(1.0f+expf(-lg.y)))*mk.y;  t.y = tg.y*mk.y;
    p.z = (1.0f/(1.0f+expf(-lg.z)))*mk.z;  t.z = tg.z*mk.z;
    p.w = (1.0f/(1.0f+expf(-lg.w)))*mk.w;  t.w = tg.w*mk.w;
    *(float4*)(pred + i) = p;
    *(float4*)(tgt + i)  = t;
}

template <bool FINAL>
__global__ __launch_bounds__(256) void skel_iter_kernel(const float* __restrict__ xin,
                                                        float* __restrict__ xout,
                                                        const float* __restrict__ other,
                                                        double* __restrict__ acc) {
    alignas(16) __shared__ float sx[4][XH * XS];   // x planes ring (23.0 KB)
    alignas(16) __shared__ float smp[34 * XS];     // mp plane (5.4 KB)

    int bx  = blockIdx.x;
    int w0  = (bx & 7) * TW;
    int h0  = ((bx >> 3) & 7) * TH;
    int gd0 = ((bx >> 6) & 7) * CD;
    int b   = bx >> 9;
    int tid = threadIdx.x;
    int r8  = tid >> 3;          // 0..31 : output row within tile
    int ow  = (tid & 7) * 4;     // 0..28 : output col vec within tile

    const float* xb = xin + b * (D * HW);
    float*       ob = xout ? (xout + b * (D * HW)) : nullptr;
    const float* otb = other + b * (D * HW);

    const float4 inf4  = make_float4( INFINITY,  INFINITY,  INFINITY,  INFINITY);
    const float4 ninf4 = make_float4(-INFINITY, -INFINITY, -INFINITY, -INFINITY);

    auto load_plane = [&](int p) {
        float* dst = sx[p & 3];
        if (p < 0 || p >= D) {
            for (int i = tid; i < 360; i += 256) {
                int r = i / 10, c = i - r * 10;
                *(float4*)&dst[r * XS + 4 * c] = inf4;
            }
        } else {
            const float* src = xb + p * HW;
            for (int i = tid; i < 360; i += 256) {
                int r = i / 10, c = i - r * 10;
                int gh = h0 - 2 + r;
                int gw = w0 - 4 + 4 * c;
                float4 v = inf4;
                if (gh >= 0 && gh < H && (unsigned)gw < 253u)
                    v = *(const float4*)(src + gh * W + gw);
                *(float4*)&dst[r * XS + 4 * c] = v;
            }
        }
    };

    load_plane(gd0 - 2);
    load_plane(gd0 - 1);

    float4 h2 = ninf4, h1 = ninf4;   // hw9 ring: planes q-2, q-1
    float4 mpc1 = ninf4;             // mp center of plane q-1
    double s0 = 0.0, s1 = 0.0;

    for (int q = gd0 - 1; q <= gd0 + CD; ++q) {
        load_plane(q + 1);
        __syncthreads();   // x[q+1] ready; prior mp/x reads complete

        bool qvalid = (q >= 0 && q < D);
        if (qvalid) {
            const float* xm = sx[(q - 1) & 3];
            const float* xc = sx[q & 3];
            const float* xp = sx[(q + 1) & 3];
            for (int i = tid; i < 306; i += 256) {
                int r = i / 9, m = i - r * 9;
                int xo = (r + 1) * XS + 4 * m;
                float4 A  = *(const float4*)&xc[xo];
                float4 Bv = *(const float4*)&xc[xo + 4];
                float4 v  = vmin4(vmin4(sh2(A, Bv), sh3(A, Bv)), Bv);
                float4 U  = *(const float4*)&xc[xo - XS];
                float4 U2 = *(const float4*)&xc[xo - XS + 4];
                v = vmin4(v, sh3(U, U2));
                float4 Dn = *(const float4*)&xc[xo + XS];
                float4 D2 = *(const float4*)&xc[xo + XS + 4];
                v = vmin4(v, sh3(Dn, D2));
                float4 Mm = *(const float4*)&xm[xo];
                float4 M2 = *(const float4*)&xm[xo + 4];
                v = vmin4(v, sh3(Mm, M2));
                float4 Pp = *(const float4*)&xp[xo];
                float4 P2 = *(const float4*)&xp[xo + 4];
                v = vmin4(v, sh3(Pp, P2));
                // mask OOB centers to -INF so the max stage ignores them
                int gh = h0 - 1 + r;
                if (gh < 0 || gh >= H) v = ninf4;
                int wb = w0 - 1 + 4 * m;
                if (wb < 0)          v.x = -INFINITY;
                if (wb + 1 >= W)     v.y = -INFINITY;
                if (wb + 2 >= W)     v.z = -INFINITY;
                if (wb + 3 >= W)     v.w = -INFINITY;
                *(float4*)&smp[r * XS + 4 * m] = v;
            }
        }
        __syncthreads();   // mp[q] ready

        // hw9[q] = 3x3 HW max of mp[q] at this thread's output positions
        float4 hc, mpcc;
        if (qvalid) {
            int base = r8 * XS + ow;
            float4 A0 = *(const float4*)&smp[base];
            float4 B0 = *(const float4*)&smp[base + 4];
            float4 A1 = *(const float4*)&smp[base + XS];
            float4 B1 = *(const float4*)&smp[base + XS + 4];
            float4 A2 = *(const float4*)&smp[base + 2 * XS];
            float4 B2 = *(const float4*)&smp[base + 2 * XS + 4];
            float4 r0 = vmax4(A0, vmax4(sh1(A0, B0), sh2(A0, B0)));
            float4 r1 = vmax4(A1, vmax4(sh1(A1, B1), sh2(A1, B1)));
            float4 r2 = vmax4(A2, vmax4(sh1(A2, B2), sh2(A2, B2)));
            hc   = vmax4(r0, vmax4(r1, r2));
            mpcc = sh1(A1, B1);
        } else {
            hc = ninf4; mpcc = ninf4;
        }

        int d = q - 1;
        if (d >= gd0 && d < gd0 + CD) {
            float4 xv = *(const float4*)&sx[d & 3][(r8 + 2) * XS + ow + 4];
            float4 mx = vmax4(h2, vmax4(h1, hc));
            float4 res;
            res.x = fmaxf(xv.x - (mx.x - mpc1.x), 0.0f);
            res.y = fmaxf(xv.y - (mx.y - mpc1.y), 0.0f);
            res.z = fmaxf(xv.z - (mx.z - mpc1.z), 0.0f);
            res.w = fmaxf(xv.w - (mx.w - mpc1.w), 0.0f);
            long off = (long)d * HW + (h0 + r8) * W + (w0 + ow);
            if constexpr (FINAL) {
                float4 ov = *(const float4*)(otb + off);
                s0 += (double)(res.x * ov.x) + (double)(res.y * ov.y)
                    + (double)(res.z * ov.z) + (double)(res.w * ov.w);
                s1 += (double)res.x + (double)res.y + (double)res.z + (double)res.w;
            } else {
                *(float4*)(ob + off) = res;
            }
        }
        h2 = h1; h1 = hc; mpc1 = mpcc;
    }

    if constexpr (FINAL) {
        for (int off = 32; off > 0; off >>= 1) {
            s0 += __shfl_down(s0, off, 64);
            s1 += __shfl_down(s1, off, 64);
        }
        if ((tid & 63) == 0) {
            atomicAdd(&acc[0], s0);
            atomicAdd(&acc[1], s1);
        }
    }
}

__global__ void final_kernel(const double* __restrict__ acc, float* __restrict__ out) {
    double clrecall = (acc[0] + 1e-12) / (acc[1] + 1e-12);
    double clacc    = (acc[2] + 1e-12) / (acc[3] + 1e-12);
    double cldice   = 2.0 * clrecall * clacc / (clrecall + clacc + 1e-12);
    out[0] = (float)(1.0 - cldice);
}

extern "C" void kernel_launch(void* const* d_in, const int* in_sizes, int n_in,
                              void* d_out, int out_size, void* d_ws, size_t ws_size,
                              hipStream_t stream) {
    const float* logits = (const float*)d_in[0];
    const float* target = (const float*)d_in[1];
    const float* mask   = (const float*)d_in[2];
    float* out = (float*)d_out;

    // Workspace layout (floats): pred | tgt | xA | xB | acc(4 doubles)
    float* pred = (float*)d_ws;
    float* tgt  = pred + NV;
    float* xA   = tgt + NV;
    float* xB   = xA + NV;
    double* acc = (double*)(xB + NV);

    hipMemsetAsync(acc, 0, 4 * sizeof(double), stream);

    dim3 blk(256);
    prep_kernel<<<dim3(NV / 1024), blk, 0, stream>>>(logits, target, mask, pred, tgt);

    dim3 sgrd(1024);  // 2 batches x 8 D-chunks x 8x8 tiles = 4 blocks/CU

    // skeletonize(tgt): tgt -> A -> B -> A -> B -> (fused reduce vs pred)
    for (int it = 0; it < 4; ++it) {
        const float* in = (it == 0) ? tgt : ((it & 1) ? xA : xB);
        float* outb = (it & 1) ? xB : xA;
        skel_iter_kernel<false><<<sgrd, blk, 0, stream>>>(in, outb, pred, acc);
    }
    skel_iter_kernel<true><<<sgrd, blk, 0, stream>>>(xB, nullptr, pred, acc);

    // skeletonize(pred): pred -> A -> B -> A -> B -> (fused reduce vs tgt)
    for (int it = 0; it < 4; ++it) {
        const float* in = (it == 0) ? pred : ((it & 1) ? xA : xB);
        float* outb = (it & 1) ? xB : xA;
        skel_iter_kernel<false><<<sgrd, blk, 0, stream>>>(in, outb, tgt, acc);
    }
    skel_iter_kernel<true><<<sgrd, blk, 0, stream>>>(xB, nullptr, tgt, acc + 2);

    final_kernel<<<1, 1, 0, stream>>>(acc, out);
}

// Round 5
// 577.626 us; speedup vs baseline: 2.8479x; 1.0060x over previous
//
#include <hip/hip_runtime.h>
#include <math.h>

// SoftclDiceLoss on (B,C,D,H,W) = (2,1,64,256,256) float32.
// Fused skeletonize iteration, R5:
//  - all LDS ops are b128 with 16-lane-quarter-aligned bank-group maps
//  - prefetch depth 2 (global->reg at top of iter, ds_write after mp compute)
//  - ONE barrier per plane (smp 2-ring, x-read hoisted pre-barrier)
//   mp[q]  = 7-point cross min of x (LDS)
//   hw9[q] = 3x3 HW-max of mp[q]   (registers, rotating ring of 3)
//   out[d=q-1] = relu(x - (max(hw9[d-1..d+1]) - mp_center[d]))

constexpr int B  = 2;
constexpr int D  = 64;
constexpr int H  = 256;
constexpr int W  = 256;
constexpr int HW = H * W;           // 65536
constexpr int NV = B * D * H * W;   // 8388608

constexpr int TH = 32, TW = 32;     // output tile
constexpr int CD = 8;               // D-chunk per block
constexpr int XS = 40;              // LDS row stride (floats)
constexpr int XH = 36;              // x plane rows (halo 2)
constexpr int MH = 34;              // mp plane rows (halo 1)
// x plane covers global cols w0-4 .. w0+35 ; x float k <-> global col w0-4+k
// mp col c <-> global col w0-1+c ; mp row r <-> global row h0-1+r

__device__ __forceinline__ float4 vmin4(float4 a, float4 b) {
    return make_float4(fminf(a.x,b.x), fminf(a.y,b.y), fminf(a.z,b.z), fminf(a.w,b.w));
}
__device__ __forceinline__ float4 vmax4(float4 a, float4 b) {
    return make_float4(fmaxf(a.x,b.x), fmaxf(a.y,b.y), fmaxf(a.z,b.z), fmaxf(a.w,b.w));
}
__device__ __forceinline__ float4 sh1(float4 a, float4 b) { return make_float4(a.y,a.z,a.w,b.x); }
__device__ __forceinline__ float4 sh2(float4 a, float4 b) { return make_float4(a.z,a.w,b.x,b.y); }
__device__ __forceinline__ float4 sh3(float4 a, float4 b) { return make_float4(a.w,b.x,b.y,b.z); }

__global__ __launch_bounds__(256) void prep_kernel(const float* __restrict__ logits,
                                                   const float* __restrict__ target,
                                                   const float* __restrict__ mask,
                                                   float* __restrict__ pred,
                                                   float* __restrict__ tgt) {
    int i = (blockIdx.x * 256 + threadIdx.x) * 4;
    float4 lg = *(const float4*)(logits + i);
    float4 tg = *(const float4*)(target + i);
    float4 mk = *(const float4*)(mask + i);
    float4 p, t;
    p.x = (1.0f/(1.0f+expf(-lg.x)))*mk.x;  t.x = tg.x*mk.x;
    p.y = (1.0f/(1.0f+expf(-lg.y)))*mk.y;  t.y = tg.y*mk.y;
    p.z = (1.0f/(1.0f+expf(-lg.z)))*mk.z;  t.z = tg.z*mk.z;
    p.w = (1.0f/(1.0f+expf(-lg.w)))*mk.w;  t.w = tg.w*mk.w;
    *(float4*)(pred + i) = p;
    *(float4*)(tgt + i)  = t;
}

template <bool FINAL>
__global__ __launch_bounds__(256) void skel_iter_kernel(const float* __restrict__ xin,
                                                        float* __restrict__ xout,
                                                        const float* __restrict__ other,
                                                        double* __restrict__ acc) {
    alignas(16) __shared__ float sx[4][XH * XS];   // x planes ring of 4 (23.0 KB)
    alignas(16) __shared__ float smp[2][MH * XS];  // mp planes ring of 2 (10.9 KB)

    int bx  = blockIdx.x;
    int w0  = (bx & 7) * TW;
    int h0  = ((bx >> 3) & 7) * TH;
    int gd0 = ((bx >> 6) & 7) * CD;
    int b   = bx >> 9;
    int tid = threadIdx.x;
    int r8  = tid >> 3;          // 0..31
    int c8  = tid & 7;           // 0..7
    int ow  = c8 * 4;

    const float* xb  = xin + b * (D * HW);
    float*       ob  = xout ? (xout + b * (D * HW)) : nullptr;
    const float* otb = other + b * (D * HW);

    const float4 inf4  = make_float4( INFINITY,  INFINITY,  INFINITY,  INFINITY);
    const float4 ninf4 = make_float4(-INFINITY, -INFINITY, -INFINITY, -INFINITY);

    // Quarter-aligned load decomposition of the 36x10 float4 plane:
    //  main: row r8 (0..31), group c8 (0..7)         - every thread
    //  aux : row 32+(tid>>3), group tid&7            - tid < 32
    //  edge: row tid>>1, group 8+(tid&1)             - tid < 72
    int  a_r = 32 + (tid >> 3), a_c = tid & 7;
    int  e_r = tid >> 1,        e_c = 8 + (tid & 1);
    bool has_a = tid < 32;
    bool has_e = tid < 72;

    auto fetch = [&](const float* src, int r, int c) -> float4 {
        int gh = h0 - 2 + r;
        int gw = w0 - 4 + 4 * c;   // always a multiple of 4: fully in or fully out
        if (gh >= 0 && gh < H && (unsigned)gw <= 252u)
            return *(const float4*)(src + gh * W + gw);
        return inf4;
    };

    float4 La, Lb, Le;
    auto issue_loads = [&](int p) {
        if (p < 0 || p >= D) { La = inf4; Lb = inf4; Le = inf4; return; }
        const float* src = xb + p * HW;
        La = fetch(src, r8, c8);
        Lb = has_a ? fetch(src, a_r, a_c) : inf4;
        Le = has_e ? fetch(src, e_r, e_c) : inf4;
    };
    auto store_plane = [&](int p) {
        float* dst = sx[p & 3];
        *(float4*)&dst[r8 * XS + 4 * c8] = La;
        if (has_a) *(float4*)&dst[a_r * XS + 4 * a_c] = Lb;
        if (has_e) *(float4*)&dst[e_r * XS + 4 * e_c] = Le;
    };

    // 7-point cross min at mp row r, group m (mp floats 4m..4m+3)
    auto cross_min = [&](const float* xm, const float* xc, const float* xp,
                         int r, int m) -> float4 {
        int xo = (r + 1) * XS + 4 * m;
        float4 A  = *(const float4*)&xc[xo];
        float4 Bv = *(const float4*)&xc[xo + 4];
        float4 v  = vmin4(vmin4(sh2(A, Bv), sh3(A, Bv)), Bv);
        float4 U  = *(const float4*)&xc[xo - XS];
        float4 U2 = *(const float4*)&xc[xo - XS + 4];
        v = vmin4(v, sh3(U, U2));
        float4 Dn = *(const float4*)&xc[xo + XS];
        float4 D2 = *(const float4*)&xc[xo + XS + 4];
        v = vmin4(v, sh3(Dn, D2));
        float4 Mm = *(const float4*)&xm[xo];
        float4 M2 = *(const float4*)&xm[xo + 4];
        v = vmin4(v, sh3(Mm, M2));
        float4 Pp = *(const float4*)&xp[xo];
        float4 P2 = *(const float4*)&xp[xo + 4];
        v = vmin4(v, sh3(Pp, P2));
        int gh = h0 - 1 + r;
        if (gh < 0 || gh >= H) return ninf4;   // OOB centers -> -INF (max ignores)
        int wb = w0 - 1 + 4 * m;
        if (wb < 0)        v.x = -INFINITY;
        if (wb + 1 >= W)   v.y = -INFINITY;
        if (wb + 2 >= W)   v.z = -INFINITY;
        if (wb + 3 >= W)   v.w = -INFINITY;
        return v;
    };

    // Prologue: planes gd0-2, gd0-1, gd0 resident before first mp compute.
    issue_loads(gd0 - 2); store_plane(gd0 - 2);
    issue_loads(gd0 - 1); store_plane(gd0 - 1);
    issue_loads(gd0);     store_plane(gd0);
    __syncthreads();

    float4 h2 = ninf4, h1 = ninf4;   // hw9 ring: planes q-2, q-1
    float4 mpc1 = ninf4;             // mp center of plane q-1
    double s0 = 0.0, s1 = 0.0;

    for (int q = gd0 - 1; q <= gd0 + CD; ++q) {
        // (1) prefetch plane q+2 into registers (latency hides under mp compute)
        bool do_load = (q + 2 <= gd0 + CD + 1);
        if (do_load) issue_loads(q + 2);

        // (2) mp[q] -> smp[q&1]. Hazard: previous reader of smp[q&1] was
        // hw9[q-2] (post-barrier_{q-2}); barrier_{q-1} separates. OK.
        bool qv = (q >= 0 && q < D);
        float* mp = smp[q & 1];
        if (qv) {
            const float* xm = sx[(q - 1) & 3];
            const float* xc = sx[q & 3];
            const float* xp = sx[(q + 1) & 3];
            *(float4*)&mp[r8 * XS + 4 * c8] = cross_min(xm, xc, xp, r8, c8);
            if (tid < 16) {
                int r = 32 + (tid >> 3);
                *(float4*)&mp[r * XS + 4 * (tid & 7)] = cross_min(xm, xc, xp, r, tid & 7);
            }
            if (tid < 34) {
                *(float4*)&mp[tid * XS + 32] = cross_min(xm, xc, xp, tid, 8);
            }
        }

        // hoist x center for out[d=q-1] (slot (q-1)&3 is stable: written at
        // iter q-3, overwritten at iter q+3)
        int d = q - 1;
        bool dv = (d >= gd0);
        float4 xv = dv ? *(const float4*)&sx[d & 3][(r8 + 2) * XS + ow + 4] : inf4;

        // (3) commit prefetched plane to slot (q+2)&3. Hazard: old content
        // x[q-2] last read pre-barrier_{q-1} (mp[q-1], xv hoist). OK.
        if (do_load) store_plane(q + 2);

        __syncthreads();   // the ONLY barrier per plane

        // (4) hw9[q]: 3x3 HW max of mp[q] (post-barrier read of smp[q&1])
        float4 hc, mpcc;
        if (qv) {
            const float* m1p = smp[q & 1];
            int base = r8 * XS + ow;
            float4 A0 = *(const float4*)&m1p[base],          B0 = *(const float4*)&m1p[base + 4];
            float4 A1 = *(const float4*)&m1p[base + XS],     B1 = *(const float4*)&m1p[base + XS + 4];
            float4 A2 = *(const float4*)&m1p[base + 2 * XS], B2 = *(const float4*)&m1p[base + 2 * XS + 4];
            float4 r0 = vmax4(A0, vmax4(sh1(A0, B0), sh2(A0, B0)));
            float4 r1 = vmax4(A1, vmax4(sh1(A1, B1), sh2(A1, B1)));
            float4 r2 = vmax4(A2, vmax4(sh1(A2, B2), sh2(A2, B2)));
            hc   = vmax4(r0, vmax4(r1, r2));
            mpcc = sh1(A1, B1);
        } else { hc = ninf4; mpcc = ninf4; }

        // (5) out[d] = relu(x - (max27 - mp_center)) ; registers only + global
        if (dv) {
            float4 mx = vmax4(h2, vmax4(h1, hc));
            float4 res;
            res.x = fmaxf(xv.x - (mx.x - mpc1.x), 0.0f);
            res.y = fmaxf(xv.y - (mx.y - mpc1.y), 0.0f);
            res.z = fmaxf(xv.z - (mx.z - mpc1.z), 0.0f);
            res.w = fmaxf(xv.w - (mx.w - mpc1.w), 0.0f);
            long off = (long)d * HW + (h0 + r8) * W + (w0 + ow);
            if constexpr (FINAL) {
                float4 ov = *(const float4*)(otb + off);
                s0 += (double)(res.x * ov.x) + (double)(res.y * ov.y)
                    + (double)(res.z * ov.z) + (double)(res.w * ov.w);
                s1 += (double)res.x + (double)res.y + (double)res.z + (double)res.w;
            } else {
                *(float4*)(ob + off) = res;
            }
        }
        h2 = h1; h1 = hc; mpc1 = mpcc;
    }

    if constexpr (FINAL) {
        for (int off = 32; off > 0; off >>= 1) {
            s0 += __shfl_down(s0, off, 64);
            s1 += __shfl_down(s1, off, 64);
        }
        if ((tid & 63) == 0) {
            atomicAdd(&acc[0], s0);
            atomicAdd(&acc[1], s1);
        }
    }
}

__global__ void final_kernel(const double* __restrict__ acc, float* __restrict__ out) {
    double clrecall = (acc[0] + 1e-12) / (acc[1] + 1e-12);
    double clacc    = (acc[2] + 1e-12) / (acc[3] + 1e-12);
    double cldice   = 2.0 * clrecall * clacc / (clrecall + clacc + 1e-12);
    out[0] = (float)(1.0 - cldice);
}

extern "C" void kernel_launch(void* const* d_in, const int* in_sizes, int n_in,
                              void* d_out, int out_size, void* d_ws, size_t ws_size,
                              hipStream_t stream) {
    const float* logits = (const float*)d_in[0];
    const float* target = (const float*)d_in[1];
    const float* mask   = (const float*)d_in[2];
    float* out = (float*)d_out;

    // Workspace layout (floats): pred | tgt | xA | xB | acc(4 doubles)
    float* pred = (float*)d_ws;
    float* tgt  = pred + NV;
    float* xA   = tgt + NV;
    float* xB   = xA + NV;
    double* acc = (double*)(xB + NV);

    hipMemsetAsync(acc, 0, 4 * sizeof(double), stream);

    dim3 blk(256);
    prep_kernel<<<dim3(NV / 1024), blk, 0, stream>>>(logits, target, mask, pred, tgt);

    dim3 sgrd(1024);  // 2 batches x 8 D-chunks x 8x8 tiles = 4 blocks/CU

    // skeletonize(tgt): tgt -> A -> B -> A -> B -> (fused reduce vs pred)
    for (int it = 0; it < 4; ++it) {
        const float* in = (it == 0) ? tgt : ((it & 1) ? xA : xB);
        float* outb = (it & 1) ? xB : xA;
        skel_iter_kernel<false><<<sgrd, blk, 0, stream>>>(in, outb, pred, acc);
    }
    skel_iter_kernel<true><<<sgrd, blk, 0, stream>>>(xB, nullptr, pred, acc);

    // skeletonize(pred): pred -> A -> B -> A -> B -> (fused reduce vs tgt)
    for (int it = 0; it < 4; ++it) {
        const float* in = (it == 0) ? pred : ((it & 1) ? xA : xB);
        float* outb = (it & 1) ? xB : xA;
        skel_iter_kernel<false><<<sgrd, blk, 0, stream>>>(in, outb, tgt, acc);
    }
    skel_iter_kernel<true><<<sgrd, blk, 0, stream>>>(xB, nullptr, tgt, acc + 2);

    final_kernel<<<1, 1, 0, stream>>>(acc, out);
}

// Round 6
// 554.965 us; speedup vs baseline: 2.9642x; 1.0408x over previous
//
#include <hip/hip_runtime.h>
#include <math.h>

// SoftclDiceLoss on (B,C,D,H,W) = (2,1,64,256,256) float32.
// Fused skeletonize iteration, R6:
//  - XS=44 (11 mod 8 = 3): distinct bank-group rotation per row for b128
//  - depth-2 register prefetch of x planes (full-iteration latency cover)
//  - XCD-chunked block swizzle for cross-dispatch L2 halo locality
//  - one barrier per plane
//   mp[q]  = 7-point cross min of x (LDS)
//   hw9[q] = 3x3 HW-max of mp[q]   (registers, rotating ring of 3)
//   out[d=q-1] = relu(x - (max(hw9[d-1..d+1]) - mp_center[d]))

constexpr int B  = 2;
constexpr int D  = 64;
constexpr int H  = 256;
constexpr int W  = 256;
constexpr int HW = H * W;           // 65536
constexpr int NV = B * D * H * W;   // 8388608

constexpr int TH = 32, TW = 32;     // output tile
constexpr int CD = 8;               // D-chunk per block
constexpr int XS = 44;              // LDS row stride (floats); 11 f4-groups mod 8 = 3
constexpr int XH = 36;              // x plane rows (halo 2)
constexpr int MH = 34;              // mp plane rows (halo 1)
// x plane covers global cols w0-4 .. w0+35 ; x float k <-> global col w0-4+k
// mp col c <-> global col w0-1+c ; mp row r <-> global row h0-1+r

__device__ __forceinline__ float4 vmin4(float4 a, float4 b) {
    return make_float4(fminf(a.x,b.x), fminf(a.y,b.y), fminf(a.z,b.z), fminf(a.w,b.w));
}
__device__ __forceinline__ float4 vmax4(float4 a, float4 b) {
    return make_float4(fmaxf(a.x,b.x), fmaxf(a.y,b.y), fmaxf(a.z,b.z), fmaxf(a.w,b.w));
}
__device__ __forceinline__ float4 sh1(float4 a, float4 b) { return make_float4(a.y,a.z,a.w,b.x); }
__device__ __forceinline__ float4 sh2(float4 a, float4 b) { return make_float4(a.z,a.w,b.x,b.y); }
__device__ __forceinline__ float4 sh3(float4 a, float4 b) { return make_float4(a.w,b.x,b.y,b.z); }

__global__ __launch_bounds__(256) void prep_kernel(const float* __restrict__ logits,
                                                   const float* __restrict__ target,
                                                   const float* __restrict__ mask,
                                                   float* __restrict__ pred,
                                                   float* __restrict__ tgt) {
    int i = (blockIdx.x * 256 + threadIdx.x) * 4;
    float4 lg = *(const float4*)(logits + i);
    float4 tg = *(const float4*)(target + i);
    float4 mk = *(const float4*)(mask + i);
    float4 p, t;
    p.x = (1.0f/(1.0f+expf(-lg.x)))*mk.x;  t.x = tg.x*mk.x;
    p.y = (1.0f/(1.0f+expf(-lg.y)))*mk.y;  t.y = tg.y*mk.y;
    p.z = (1.0f/(1.0f+expf(-lg.z)))*mk.z;  t.z = tg.z*mk.z;
    p.w = (1.0f/(1.0f+expf(-lg.w)))*mk.w;  t.w = tg.w*mk.w;
    *(float4*)(pred + i) = p;
    *(float4*)(tgt + i)  = t;
}

template <bool FINAL>
__global__ __launch_bounds__(256) void skel_iter_kernel(const float* __restrict__ xin,
                                                        float* __restrict__ xout,
                                                        const float* __restrict__ other,
                                                        double* __restrict__ acc) {
    alignas(16) __shared__ float sx[4][XH * XS];   // x planes ring of 4 (24.75 KB)
    alignas(16) __shared__ float smp[2][MH * XS];  // mp planes ring of 2 (11.7 KB)

    // XCD-chunked swizzle: HW round-robins blockIdx%8 across XCDs; this makes
    // each XCD own 128 consecutive LOGICAL blocks (= 1 batch x 2 D-chunks x
    // all 8x8 HW tiles) so halo re-reads across ping-pong dispatches hit the
    // same XCD's L2.
    int hwb = blockIdx.x;
    int bx  = (hwb & 7) * 128 + (hwb >> 3);

    int w0  = (bx & 7) * TW;
    int h0  = ((bx >> 3) & 7) * TH;
    int gd0 = ((bx >> 6) & 7) * CD;
    int b   = bx >> 9;
    int tid = threadIdx.x;
    int r8  = tid >> 3;          // 0..31
    int c8  = tid & 7;           // 0..7
    int ow  = c8 * 4;

    const float* xb  = xin + b * (D * HW);
    float*       ob  = xout ? (xout + b * (D * HW)) : nullptr;
    const float* otb = other + b * (D * HW);

    const float4 inf4  = make_float4( INFINITY,  INFINITY,  INFINITY,  INFINITY);
    const float4 ninf4 = make_float4(-INFINITY, -INFINITY, -INFINITY, -INFINITY);

    // Quarter-aligned decomposition of the 36x10 float4 plane:
    //  main: row r8 (0..31), group c8 (0..7)         - every thread
    //  aux : row 32+(tid>>3), group tid&7            - tid < 32
    //  edge: row tid>>1, group 8+(tid&1)             - tid < 72
    int  a_r = 32 + (tid >> 3), a_c = tid & 7;
    int  e_r = tid >> 1,        e_c = 8 + (tid & 1);
    bool has_a = tid < 32;
    bool has_e = tid < 72;

    auto fetch = [&](const float* src, int r, int c) -> float4 {
        int gh = h0 - 2 + r;
        int gw = w0 - 4 + 4 * c;   // multiple of 4: fully in or fully out
        if (gh >= 0 && gh < H && (unsigned)gw <= 252u)
            return *(const float4*)(src + gh * W + gw);
        return inf4;
    };

    float4 La, Lb, Le;           // pending plane (issued previous iter)
    auto issue_loads = [&](int p) {
        if (p < 0 || p >= D) { La = inf4; Lb = inf4; Le = inf4; return; }
        const float* src = xb + p * HW;
        La = fetch(src, r8, c8);
        Lb = has_a ? fetch(src, a_r, a_c) : inf4;
        Le = has_e ? fetch(src, e_r, e_c) : inf4;
    };
    auto store_vals = [&](int p, float4 va, float4 vb, float4 ve) {
        float* dst = sx[p & 3];
        *(float4*)&dst[r8 * XS + 4 * c8] = va;
        if (has_a) *(float4*)&dst[a_r * XS + 4 * a_c] = vb;
        if (has_e) *(float4*)&dst[e_r * XS + 4 * e_c] = ve;
    };

    // 7-point cross min at mp row r, group m (mp floats 4m..4m+3)
    auto cross_min = [&](const float* xm, const float* xc, const float* xp,
                         int r, int m) -> float4 {
        int xo = (r + 1) * XS + 4 * m;
        float4 A  = *(const float4*)&xc[xo];
        float4 Bv = *(const float4*)&xc[xo + 4];
        float4 v  = vmin4(vmin4(sh2(A, Bv), sh3(A, Bv)), Bv);
        float4 U  = *(const float4*)&xc[xo - XS];
        float4 U2 = *(const float4*)&xc[xo - XS + 4];
        v = vmin4(v, sh3(U, U2));
        float4 Dn = *(const float4*)&xc[xo + XS];
        float4 D2 = *(const float4*)&xc[xo + XS + 4];
        v = vmin4(v, sh3(Dn, D2));
        float4 Mm = *(const float4*)&xm[xo];
        float4 M2 = *(const float4*)&xm[xo + 4];
        v = vmin4(v, sh3(Mm, M2));
        float4 Pp = *(const float4*)&xp[xo];
        float4 P2 = *(const float4*)&xp[xo + 4];
        v = vmin4(v, sh3(Pp, P2));
        int gh = h0 - 1 + r;
        if (gh < 0 || gh >= H) return ninf4;   // OOB centers -> -INF (max ignores)
        int wb = w0 - 1 + 4 * m;
        if (wb < 0)        v.x = -INFINITY;
        if (wb + 1 >= W)   v.y = -INFINITY;
        if (wb + 2 >= W)   v.z = -INFINITY;
        if (wb + 3 >= W)   v.w = -INFINITY;
        return v;
    };

    // Prologue: planes gd0-2..gd0 resident; pending regs hold plane gd0+1.
    issue_loads(gd0 - 2); store_vals(gd0 - 2, La, Lb, Le);
    issue_loads(gd0 - 1); store_vals(gd0 - 1, La, Lb, Le);
    issue_loads(gd0);     store_vals(gd0,     La, Lb, Le);
    issue_loads(gd0 + 1);
    __syncthreads();

    float4 h2 = ninf4, h1 = ninf4;   // hw9 ring: planes q-2, q-1
    float4 mpc1 = ninf4;             // mp center of plane q-1
    double s0 = 0.0, s1 = 0.0;

    for (int q = gd0 - 1; q <= gd0 + CD; ++q) {
        // (1) capture pending plane (q+2), issue loads for q+3 (depth-2)
        float4 Ca = La, Cb = Lb, Ce = Le;
        int cp = q + 2;
        if (q + 3 <= gd0 + CD + 1) issue_loads(q + 3);

        // (2) mp[q] -> smp[q&1]. Previous reader of smp[q&1] was hw9[q-2]
        // (post-barrier_{q-2}); barrier_{q-1} separates. OK.
        bool qv = (q >= 0 && q < D);
        float* mp = smp[q & 1];
        if (qv) {
            const float* xm = sx[(q - 1) & 3];
            const float* xc = sx[q & 3];
            const float* xp = sx[(q + 1) & 3];
            *(float4*)&mp[r8 * XS + 4 * c8] = cross_min(xm, xc, xp, r8, c8);
            if (tid < 16) {
                int r = 32 + (tid >> 3);
                *(float4*)&mp[r * XS + 4 * (tid & 7)] = cross_min(xm, xc, xp, r, tid & 7);
            }
            if (tid < 34) {
                *(float4*)&mp[tid * XS + 32] = cross_min(xm, xc, xp, tid, 8);
            }
        }

        // hoist x center for out[d=q-1] (slot (q-1)&3 written at iter q-3,
        // overwritten at iter q+3 -> stable here)
        int d = q - 1;
        bool dv = (d >= gd0);
        float4 xv = dv ? *(const float4*)&sx[d & 3][(r8 + 2) * XS + ow + 4] : inf4;

        // (3) commit plane cp=q+2 to slot cp&3. Old content x[q-2] last read
        // at iter q-1 pre-barrier_{q-1}; one barrier between. OK.
        if (cp <= gd0 + CD + 1) store_vals(cp, Ca, Cb, Ce);

        __syncthreads();   // the ONLY barrier per plane

        // (4) hw9[q]: 3x3 HW max of mp[q] (post-barrier read of smp[q&1])
        float4 hc, mpcc;
        if (qv) {
            const float* m1p = smp[q & 1];
            int base = r8 * XS + ow;
            float4 A0 = *(const float4*)&m1p[base],          B0 = *(const float4*)&m1p[base + 4];
            float4 A1 = *(const float4*)&m1p[base + XS],     B1 = *(const float4*)&m1p[base + XS + 4];
            float4 A2 = *(const float4*)&m1p[base + 2 * XS], B2 = *(const float4*)&m1p[base + 2 * XS + 4];
            float4 r0 = vmax4(A0, vmax4(sh1(A0, B0), sh2(A0, B0)));
            float4 r1 = vmax4(A1, vmax4(sh1(A1, B1), sh2(A1, B1)));
            float4 r2 = vmax4(A2, vmax4(sh1(A2, B2), sh2(A2, B2)));
            hc   = vmax4(r0, vmax4(r1, r2));
            mpcc = sh1(A1, B1);
        } else { hc = ninf4; mpcc = ninf4; }

        // (5) out[d] = relu(x - (max27 - mp_center))
        if (dv) {
            float4 mx = vmax4(h2, vmax4(h1, hc));
            float4 res;
            res.x = fmaxf(xv.x - (mx.x - mpc1.x), 0.0f);
            res.y = fmaxf(xv.y - (mx.y - mpc1.y), 0.0f);
            res.z = fmaxf(xv.z - (mx.z - mpc1.z), 0.0f);
            res.w = fmaxf(xv.w - (mx.w - mpc1.w), 0.0f);
            long off = (long)d * HW + (h0 + r8) * W + (w0 + ow);
            if constexpr (FINAL) {
                float4 ov = *(const float4*)(otb + off);
                s0 += (double)(res.x * ov.x) + (double)(res.y * ov.y)
                    + (double)(res.z * ov.z) + (double)(res.w * ov.w);
                s1 += (double)res.x + (double)res.y + (double)res.z + (double)res.w;
            } else {
                *(float4*)(ob + off) = res;
            }
        }
        h2 = h1; h1 = hc; mpc1 = mpcc;
    }

    if constexpr (FINAL) {
        for (int off = 32; off > 0; off >>= 1) {
            s0 += __shfl_down(s0, off, 64);
            s1 += __shfl_down(s1, off, 64);
        }
        if ((tid & 63) == 0) {
            atomicAdd(&acc[0], s0);
            atomicAdd(&acc[1], s1);
        }
    }
}

__global__ void final_kernel(const double* __restrict__ acc, float* __restrict__ out) {
    double clrecall = (acc[0] + 1e-12) / (acc[1] + 1e-12);
    double clacc    = (acc[2] + 1e-12) / (acc[3] + 1e-12);
    double cldice   = 2.0 * clrecall * clacc / (clrecall + clacc + 1e-12);
    out[0] = (float)(1.0 - cldice);
}

extern "C" void kernel_launch(void* const* d_in, const int* in_sizes, int n_in,
                              void* d_out, int out_size, void* d_ws, size_t ws_size,
                              hipStream_t stream) {
    const float* logits = (const float*)d_in[0];
    const float* target = (const float*)d_in[1];
    const float* mask   = (const float*)d_in[2];
    float* out = (float*)d_out;

    // Workspace layout (floats): pred | tgt | xA | xB | acc(4 doubles)
    float* pred = (float*)d_ws;
    float* tgt  = pred + NV;
    float* xA   = tgt + NV;
    float* xB   = xA + NV;
    double* acc = (double*)(xB + NV);

    hipMemsetAsync(acc, 0, 4 * sizeof(double), stream);

    dim3 blk(256);
    prep_kernel<<<dim3(NV / 1024), blk, 0, stream>>>(logits, target, mask, pred, tgt);

    dim3 sgrd(1024);  // 2 batches x 8 D-chunks x 8x8 tiles = 4 blocks/CU

    // skeletonize(tgt): tgt -> A -> B -> A -> B -> (fused reduce vs pred)
    for (int it = 0; it < 4; ++it) {
        const float* in = (it == 0) ? tgt : ((it & 1) ? xA : xB);
        float* outb = (it & 1) ? xB : xA;
        skel_iter_kernel<false><<<sgrd, blk, 0, stream>>>(in, outb, pred, acc);
    }
    skel_iter_kernel<true><<<sgrd, blk, 0, stream>>>(xB, nullptr, pred, acc);

    // skeletonize(pred): pred -> A -> B -> A -> B -> (fused reduce vs tgt)
    for (int it = 0; it < 4; ++it) {
        const float* in = (it == 0) ? pred : ((it & 1) ? xA : xB);
        float* outb = (it & 1) ? xB : xA;
        skel_iter_kernel<false><<<sgrd, blk, 0, stream>>>(in, outb, tgt, acc);
    }
    skel_iter_kernel<true><<<sgrd, blk, 0, stream>>>(xB, nullptr, tgt, acc + 2);

    final_kernel<<<1, 1, 0, stream>>>(acc, out);
}